// Round 5
// baseline (187.986 us; speedup 1.0000x reference)
//
#include <hip/hip_runtime.h>
#include <hip/hip_bf16.h>

#define B 8
#define T 1024
#define E 128
#define H 8
#define DH 16
#define E3 384

typedef __attribute__((ext_vector_type(8))) short short8;
typedef __attribute__((ext_vector_type(4))) short short4s;
typedef __attribute__((ext_vector_type(4))) float f32x4;

// fp32 -> bf16 (round-to-nearest-even), bit pattern in a short
static __device__ inline short bf16s(float x) {
    union { float f; unsigned u; } v; v.f = x;
    unsigned r = v.u + 0x7fffu + ((v.u >> 16) & 1u);
    return (short)(r >> 16);
}

// ---------------------------------------------------------------------------
// Kernel 0: pack win into bf16 K=256 complex-packed layout.
// ---------------------------------------------------------------------------
__global__ void pack_win_kernel(
    const float* __restrict__ win_re, const float* __restrict__ win_im,
    short* __restrict__ Wp_re, short* __restrict__ Wp_im)
{
    int idx = blockIdx.x * 256 + threadIdx.x;   // [0, 384*128)
    int j = idx >> 7, e = idx & 127;
    float wr = win_re[idx], wi = win_im[idx];
    Wp_re[j*256 + e]       = bf16s(wr);
    Wp_re[j*256 + 128 + e] = bf16s(-wi);
    Wp_im[j*256 + e]       = bf16s(wi);
    Wp_im[j*256 + 128 + e] = bf16s(wr);
}

// ---------------------------------------------------------------------------
// Kernel 1: fuse output linears: wf = wt @ wout, bf = wt @ bout + bt (complex)
// Emits wf directly in packed bf16 layout, bias in fp32.
// ---------------------------------------------------------------------------
__global__ void fuse_weights_kernel(
    const float* __restrict__ wout_re, const float* __restrict__ wout_im,
    const float* __restrict__ bout_re, const float* __restrict__ bout_im,
    const float* __restrict__ wt_re,   const float* __restrict__ wt_im,
    const float* __restrict__ bt_re,   const float* __restrict__ bt_im,
    short* __restrict__ Wfp_re, short* __restrict__ Wfp_im,
    float* __restrict__ bf_re, float* __restrict__ bf_im)
{
    int idx = blockIdx.x * blockDim.x + threadIdx.x;   // [0, E*E)
    int j = idx >> 7, e = idx & 127;
    float ar = 0.f, ai = 0.f;
    for (int m = 0; m < E; ++m) {
        float tr = wt_re[j*E+m], ti = wt_im[j*E+m];
        float pr = wout_re[m*E+e], pi = wout_im[m*E+e];
        ar += tr*pr - ti*pi;
        ai += tr*pi + ti*pr;
    }
    Wfp_re[j*256 + e]       = bf16s(ar);
    Wfp_re[j*256 + 128 + e] = bf16s(-ai);
    Wfp_im[j*256 + e]       = bf16s(ai);
    Wfp_im[j*256 + 128 + e] = bf16s(ar);
    if (idx < E) {
        float br = bt_re[idx], bi = bt_im[idx];
        for (int m = 0; m < E; ++m) {
            float tr = wt_re[idx*E+m], ti = wt_im[idx*E+m];
            br += tr*bout_re[m] - ti*bout_im[m];
            bi += tr*bout_im[m] + ti*bout_re[m];
        }
        bf_re[idx] = br; bf_im[idx] = bi;
    }
}

// ---------------------------------------------------------------------------
// Kernel 2: MFMA QKV projection with fragment-ready packed outputs.
//   Qpk/Kpk : bf16 [bh][t][32]   (k<16: re(dh), k>=16: im(dh)); q scaled 0.25
//   Vtre/Vtim: bf16 [bh][dh][T]  transposed AND key-interleaved per 32-block:
//     within each 32-t block, position kk holds t where kk = 2*tloc (tloc<16)
//     or 2*(tloc-16)+1 (tloc>=16) -- matches attention's P pack order.
// ---------------------------------------------------------------------------
__global__ __launch_bounds__(256) void qkv_mfma_kernel(
    const float* __restrict__ x_re, const float* __restrict__ x_im,
    const short* __restrict__ Wp_re, const short* __restrict__ Wp_im,
    const float* __restrict__ bin_re, const float* __restrict__ bin_im,
    short* __restrict__ Qpk, short* __restrict__ Kpk,
    short* __restrict__ Vtre, short* __restrict__ Vtim)
{
    int tid  = threadIdx.x;
    int wave = tid >> 6, lane = tid & 63;
    int col  = lane & 15, quad = lane >> 4;
    int ttile = blockIdx.x;            // [0, 512)
    int b  = ttile >> 6;
    int tb = (ttile & 63) * 16 + col;  // t within batch (this lane's n index)

    // X fragments for all 8 k-tiles: B[n=col][k=quad*8+jj]
    short8 xf[8];
    #pragma unroll
    for (int kt = 0; kt < 8; ++kt) {
        const float* xs = (kt < 4) ? x_re : x_im;
        int e0 = (kt & 3) * 32 + quad * 8;
        #pragma unroll
        for (int jj = 0; jj < 8; ++jj) {
            float xv = xs[((long)(b*E + e0 + jj))*T + tb];
            xf[kt][jj] = bf16s(xv);
        }
    }

    const f32x4 zero = {0.f,0.f,0.f,0.f};
    for (int ni = 0; ni < 12; ++ni) {
        int nt = wave * 12 + ni;           // [0,48)
        int is_im = nt >= 24;
        int jt = is_im ? nt - 24 : nt;     // [0,24): which*8 + h
        const short* Wsel = is_im ? Wp_im : Wp_re;
        const short* wrow = &Wsel[(jt*16 + col)*256 + quad*8];
        f32x4 acc = zero;
        #pragma unroll
        for (int kt = 0; kt < 8; ++kt) {
            short8 af = *(const short8*)(wrow + kt*32);
            acc = __builtin_amdgcn_mfma_f32_16x16x32_bf16(af, xf[kt], acc, 0, 0, 0);
        }
        int which = jt >> 3;               // 0 q, 1 k, 2 v
        int h = jt & 7;
        float scale = (which == 0) ? 0.25f : 1.0f;
        const float* bias = is_im ? bin_im : bin_re;
        f32x4 res;
        #pragma unroll
        for (int r = 0; r < 4; ++r) {
            int jg = which*128 + h*16 + quad*4 + r;
            res[r] = (acc[r] + bias[jg]) * scale;
        }
        long bh = b*H + h;
        if (which == 2) {
            // V transposed + interleaved: Vt[bh][dh][blk*32 + kk]
            short* vt = is_im ? Vtim : Vtre;
            int tloc = tb & 31, tblk = tb & ~31;
            int kk = (tloc < 16) ? (2*tloc) : (2*(tloc-16)+1);
            #pragma unroll
            for (int r = 0; r < 4; ++r)
                vt[(bh*DH + quad*4 + r)*T + tblk + kk] = bf16s(res[r]);
        } else {
            short* qk = (which == 0) ? Qpk : Kpk;
            short4s pk;
            #pragma unroll
            for (int r = 0; r < 4; ++r) pk[r] = bf16s(res[r]);
            *(short4s*)&qk[(bh*T + tb)*32 + is_im*16 + quad*4] = pk;
        }
    }
}

// ---------------------------------------------------------------------------
// Kernel 3: MFMA flash attention, 3-stage software pipeline, no barriers.
// iter i: load frags(tile i+1) | scores+exp(tile i) -> packed-bf16 LDS |
//         PV+rowsum MFMAs (tile i-1).
// P stored as bf16 pairs at k-pos (2c,2c+1) <-> keys (c, c+16); V matches
// that interleave (written by qkv). Row-sums via ones-MFMA (lacc).
// Grid 1D: id = qt*64 + bh (XCD pinning).
// ---------------------------------------------------------------------------
__global__ __launch_bounds__(256) void attn_mfma_kernel(
    const short* __restrict__ Qpk, const short* __restrict__ Kpk,
    const short* __restrict__ Vtre, const short* __restrict__ Vtim,
    short* __restrict__ Opk)
{
    // per-wave double-buffered P: 16 rows x 40 shorts (80B rows: 16B-aligned,
    // <=2-way banks on both the b32 writes and b128 reads)
    __shared__ __align__(16) short Pb[4][2][16*40];

    int id   = blockIdx.x;
    int bh   = id & 63;
    int q0   = (id >> 6) * 64;
    int tid  = threadIdx.x;
    int wave = tid >> 6;
    int lane = tid & 63;
    int col  = lane & 15;
    int quad = lane >> 4;

    long kq_base = (long)bh * T * 32;
    long vt_base = (long)bh * DH * T + (long)col * T;

    short8 qfrag = *(const short8*)&Qpk[kq_base + (long)(q0 + wave*16 + col)*32 + quad*8];

    const short* Kb = &Kpk[kq_base];
    const short* Vr = &Vtre[vt_base];
    const short* Vi = &Vtim[vt_base];

    short8 ones;
    #pragma unroll
    for (int i = 0; i < 8; ++i) ones[i] = (short)0x3F80;   // bf16 1.0

    f32x4 oaccr = {0.f,0.f,0.f,0.f};
    f32x4 oacci = {0.f,0.f,0.f,0.f};
    f32x4 lacc  = {0.f,0.f,0.f,0.f};
    const f32x4 zero = {0.f,0.f,0.f,0.f};
    short* Pw0 = &Pb[wave][0][0];
    short* Pw1 = &Pb[wave][1][0];

    // prologue: tile 0 fragments
    short8 kf0c = *(const short8*)&Kb[(long)(col)*32 + quad*8];
    short8 kf1c = *(const short8*)&Kb[(long)(16 + col)*32 + quad*8];
    short8 vrc  = *(const short8*)&Vr[quad*8];
    short8 vic  = *(const short8*)&Vi[quad*8];
    short8 vrp = vrc, vip = vic;

    #pragma unroll 2
    for (int i = 0; i < 32; ++i) {
        // stage A: loads for tile i+1 (OOB at i=31 reads adjacent ws arrays -- unused)
        int k1 = (i + 1) * 32;
        short8 kf0n = *(const short8*)&Kb[(long)(k1 + col)*32 + quad*8];
        short8 kf1n = *(const short8*)&Kb[(long)(k1 + 16 + col)*32 + quad*8];
        short8 vrn  = *(const short8*)&Vr[k1 + quad*8];
        short8 vin  = *(const short8*)&Vi[k1 + quad*8];

        // stage B: scores + exp for tile i, packed-bf16 P into LDS
        f32x4 s0 = __builtin_amdgcn_mfma_f32_16x16x32_bf16(qfrag, kf0c, zero, 0, 0, 0);
        f32x4 s1 = __builtin_amdgcn_mfma_f32_16x16x32_bf16(qfrag, kf1c, zero, 0, 0, 0);
        short* Pw = (i & 1) ? Pw1 : Pw0;
        #pragma unroll
        for (int r = 0; r < 4; ++r) {
            float2 p; p.x = __expf(s0[r]); p.y = __expf(s1[r]);
            *(__hip_bfloat162*)&Pw[(quad*4 + r)*40 + col*2] = __float22bfloat162_rn(p);
        }

        // stage C: PV + rowsum for tile i-1
        if (i > 0) {
            const short* Pr = ((i - 1) & 1) ? Pw1 : Pw0;
            short8 af = *(const short8*)&Pr[col*40 + quad*8];
            oaccr = __builtin_amdgcn_mfma_f32_16x16x32_bf16(af, vrp, oaccr, 0, 0, 0);
            oacci = __builtin_amdgcn_mfma_f32_16x16x32_bf16(af, vip, oacci, 0, 0, 0);
            lacc  = __builtin_amdgcn_mfma_f32_16x16x32_bf16(af, ones, lacc, 0, 0, 0);
        }
        vrp = vrc; vip = vic;
        vrc = vrn; vic = vin; kf0c = kf0n; kf1c = kf1n;
    }
    // epilogue: PV for tile 31
    {
        const short* Pr = (31 & 1) ? Pw1 : Pw0;
        short8 af = *(const short8*)&Pr[col*40 + quad*8];
        oaccr = __builtin_amdgcn_mfma_f32_16x16x32_bf16(af, vrp, oaccr, 0, 0, 0);
        oacci = __builtin_amdgcn_mfma_f32_16x16x32_bf16(af, vip, oacci, 0, 0, 0);
        lacc  = __builtin_amdgcn_mfma_f32_16x16x32_bf16(af, ones, lacc, 0, 0, 0);
    }

    int b = bh >> 3, h = bh & 7;
    #pragma unroll
    for (int r = 0; r < 4; ++r) {
        float inv = 1.0f / lacc[r];           // rowsum(q) replicated across cols
        int q = q0 + wave*16 + quad*4 + r;
        long orow = ((long)(b*T + q))*256 + h*16 + col;
        Opk[orow]       = bf16s(oaccr[r] * inv);
        Opk[orow + 128] = bf16s(oacci[r] * inv);
    }
}

// ---------------------------------------------------------------------------
// Kernel 4: MFMA output projection, conversion-free B-operand from Opk.
// D[j][t] = sum_k Wf[j][k]*O[t][k], K=256. Scatter-store to out [2,B,E,T].
// ---------------------------------------------------------------------------
__global__ __launch_bounds__(256) void outproj_mfma_kernel(
    const short* __restrict__ Opk,
    const short* __restrict__ Wfp_re, const short* __restrict__ Wfp_im,
    const float* __restrict__ bf_re, const float* __restrict__ bf_im,
    float* __restrict__ out)
{
    int tid  = threadIdx.x;
    int wave = tid >> 6, lane = tid & 63;
    int col  = lane & 15, quad = lane >> 4;
    int ttile = blockIdx.x;            // [0,512)
    int b  = ttile >> 6;
    int tb = (ttile & 63) * 16 + col;
    long trow = (long)b*T + tb;

    short8 xf[8];
    #pragma unroll
    for (int kt = 0; kt < 8; ++kt)
        xf[kt] = *(const short8*)&Opk[trow*256 + kt*32 + quad*8];

    const f32x4 zero = {0.f,0.f,0.f,0.f};
    #pragma unroll
    for (int ni = 0; ni < 4; ++ni) {
        int nt = wave * 4 + ni;            // [0,16)
        int is_im = nt >= 8;
        int jt = is_im ? nt - 8 : nt;      // [0,8)
        const short* Wsel = is_im ? Wfp_im : Wfp_re;
        const short* wrow = &Wsel[(jt*16 + col)*256 + quad*8];
        f32x4 acc = zero;
        #pragma unroll
        for (int kt = 0; kt < 8; ++kt) {
            short8 af = *(const short8*)(wrow + kt*32);
            acc = __builtin_amdgcn_mfma_f32_16x16x32_bf16(af, xf[kt], acc, 0, 0, 0);
        }
        const float* bias = is_im ? bf_im : bf_re;
        long part = is_im ? (long)B*E*T : 0;
        #pragma unroll
        for (int r = 0; r < 4; ++r) {
            int j = jt*16 + quad*4 + r;
            out[part + ((long)(b*E + j))*T + tb] = acc[r] + bias[j];
        }
    }
}

// ---------------------------------------------------------------------------
extern "C" void kernel_launch(void* const* d_in, const int* in_sizes, int n_in,
                              void* d_out, int out_size, void* d_ws, size_t ws_size,
                              hipStream_t stream)
{
    const float* x_re    = (const float*)d_in[0];
    const float* x_im    = (const float*)d_in[1];
    const float* win_re  = (const float*)d_in[2];
    const float* win_im  = (const float*)d_in[3];
    const float* bin_re  = (const float*)d_in[4];
    const float* bin_im  = (const float*)d_in[5];
    const float* wout_re = (const float*)d_in[6];
    const float* wout_im = (const float*)d_in[7];
    const float* bout_re = (const float*)d_in[8];
    const float* bout_im = (const float*)d_in[9];
    const float* wt_re   = (const float*)d_in[10];
    const float* wt_im   = (const float*)d_in[11];
    const float* bt_re   = (const float*)d_in[12];
    const float* bt_im   = (const float*)d_in[13];
    float* out = (float*)d_out;

    // workspace layout (shorts/floats)
    short* Qpk  = (short*)d_ws;                       // 64*1024*32 = 2M shorts
    short* Kpk  = Qpk + (long)B*H*T*32;
    short* Vtre = Kpk + (long)B*H*T*32;               // 64*16*1024 = 1M shorts
    short* Vtim = Vtre + (long)B*H*DH*T;
    short* Opk  = Vtim + (long)B*H*DH*T;              // 8*1024*256 = 2M shorts
    short* Wp_re  = Opk + (long)B*T*256;
    short* Wp_im  = Wp_re + E3*256;
    short* Wfp_re = Wp_im + E3*256;
    short* Wfp_im = Wfp_re + E*256;
    float* bf_re  = (float*)(Wfp_im + E*256);
    float* bf_im  = bf_re + E;

    pack_win_kernel<<<dim3(E3*E/256), dim3(256), 0, stream>>>(
        win_re, win_im, Wp_re, Wp_im);

    fuse_weights_kernel<<<dim3(E*E/256), dim3(256), 0, stream>>>(
        wout_re, wout_im, bout_re, bout_im, wt_re, wt_im, bt_re, bt_im,
        Wfp_re, Wfp_im, bf_re, bf_im);

    qkv_mfma_kernel<<<dim3(T*B/16), dim3(256), 0, stream>>>(
        x_re, x_im, Wp_re, Wp_im, bin_re, bin_im,
        Qpk, Kpk, Vtre, Vtim);

    attn_mfma_kernel<<<dim3((T/64) * B*H), dim3(256), 0, stream>>>(
        Qpk, Kpk, Vtre, Vtim, Opk);

    outproj_mfma_kernel<<<dim3(T*B/16), dim3(256), 0, stream>>>(
        Opk, Wfp_re, Wfp_im, bf_re, bf_im, out);
}

// Round 6
// 187.656 us; speedup vs baseline: 1.0018x; 1.0018x over previous
//
#include <hip/hip_runtime.h>
#include <hip/hip_bf16.h>

#define B 8
#define T 1024
#define E 128
#define H 8
#define DH 16
#define E3 384

typedef __attribute__((ext_vector_type(8))) short short8;
typedef __attribute__((ext_vector_type(4))) short short4s;
typedef __attribute__((ext_vector_type(4))) float f32x4;

// fp32 -> bf16 (round-to-nearest-even), bit pattern in a short
static __device__ inline short bf16s(float x) {
    union { float f; unsigned u; } v; v.f = x;
    unsigned r = v.u + 0x7fffu + ((v.u >> 16) & 1u);
    return (short)(r >> 16);
}

// ---------------------------------------------------------------------------
// Kernel 0: pack win into bf16 K=256 complex-packed layout.
// ---------------------------------------------------------------------------
__global__ void pack_win_kernel(
    const float* __restrict__ win_re, const float* __restrict__ win_im,
    short* __restrict__ Wp_re, short* __restrict__ Wp_im)
{
    int idx = blockIdx.x * 256 + threadIdx.x;   // [0, 384*128)
    int j = idx >> 7, e = idx & 127;
    float wr = win_re[idx], wi = win_im[idx];
    Wp_re[j*256 + e]       = bf16s(wr);
    Wp_re[j*256 + 128 + e] = bf16s(-wi);
    Wp_im[j*256 + e]       = bf16s(wi);
    Wp_im[j*256 + 128 + e] = bf16s(wr);
}

// ---------------------------------------------------------------------------
// Kernel 1: fuse output linears: wf = wt @ wout, bf = wt @ bout + bt (complex)
// Emits wf directly in packed bf16 layout, bias in fp32.
// ---------------------------------------------------------------------------
__global__ void fuse_weights_kernel(
    const float* __restrict__ wout_re, const float* __restrict__ wout_im,
    const float* __restrict__ bout_re, const float* __restrict__ bout_im,
    const float* __restrict__ wt_re,   const float* __restrict__ wt_im,
    const float* __restrict__ bt_re,   const float* __restrict__ bt_im,
    short* __restrict__ Wfp_re, short* __restrict__ Wfp_im,
    float* __restrict__ bf_re, float* __restrict__ bf_im)
{
    int idx = blockIdx.x * blockDim.x + threadIdx.x;   // [0, E*E)
    int j = idx >> 7, e = idx & 127;
    float ar = 0.f, ai = 0.f;
    for (int m = 0; m < E; ++m) {
        float tr = wt_re[j*E+m], ti = wt_im[j*E+m];
        float pr = wout_re[m*E+e], pi = wout_im[m*E+e];
        ar += tr*pr - ti*pi;
        ai += tr*pi + ti*pr;
    }
    Wfp_re[j*256 + e]       = bf16s(ar);
    Wfp_re[j*256 + 128 + e] = bf16s(-ai);
    Wfp_im[j*256 + e]       = bf16s(ai);
    Wfp_im[j*256 + 128 + e] = bf16s(ar);
    if (idx < E) {
        float br = bt_re[idx], bi = bt_im[idx];
        for (int m = 0; m < E; ++m) {
            float tr = wt_re[idx*E+m], ti = wt_im[idx*E+m];
            br += tr*bout_re[m] - ti*bout_im[m];
            bi += tr*bout_im[m] + ti*bout_re[m];
        }
        bf_re[idx] = br; bf_im[idx] = bi;
    }
}

// ---------------------------------------------------------------------------
// Kernel 2: MFMA QKV projection, fragment-ready packed outputs.
// Grid 1024: id = ttile*2 + half; half=0 computes all re outputs, half=1 im.
// (2x blocks vs r5 -> 4 waves/SIMD; x-gather duplicated, MFMA work halved.)
//   Qpk/Kpk : bf16 [bh][t][32]; q scaled 0.25
//   Vtre/Vtim: bf16 [bh][dh][T] transposed + per-32-block key-interleaved
// ---------------------------------------------------------------------------
__global__ __launch_bounds__(256) void qkv_mfma_kernel(
    const float* __restrict__ x_re, const float* __restrict__ x_im,
    const short* __restrict__ Wp_re, const short* __restrict__ Wp_im,
    const float* __restrict__ bin_re, const float* __restrict__ bin_im,
    short* __restrict__ Qpk, short* __restrict__ Kpk,
    short* __restrict__ Vtre, short* __restrict__ Vtim)
{
    int tid  = threadIdx.x;
    int wave = tid >> 6, lane = tid & 63;
    int col  = lane & 15, quad = lane >> 4;
    int id = blockIdx.x;               // [0, 1024)
    int ttile = id >> 1;
    int is_im = id & 1;
    int b  = ttile >> 6;
    int tb = (ttile & 63) * 16 + col;  // t within batch (this lane's n index)

    // X fragments for all 8 k-tiles: B[n=col][k=quad*8+jj]
    short8 xf[8];
    #pragma unroll
    for (int kt = 0; kt < 8; ++kt) {
        const float* xs = (kt < 4) ? x_re : x_im;
        int e0 = (kt & 3) * 32 + quad * 8;
        #pragma unroll
        for (int jj = 0; jj < 8; ++jj) {
            float xv = xs[((long)(b*E + e0 + jj))*T + tb];
            xf[kt][jj] = bf16s(xv);
        }
    }

    const short* Wsel = is_im ? Wp_im : Wp_re;
    const float* bias = is_im ? bin_im : bin_re;
    const f32x4 zero = {0.f,0.f,0.f,0.f};

    for (int ni = 0; ni < 6; ++ni) {
        int jt = wave * 6 + ni;            // [0,24): which*8 + h
        const short* wrow = &Wsel[(jt*16 + col)*256 + quad*8];
        f32x4 acc = zero;
        #pragma unroll
        for (int kt = 0; kt < 8; ++kt) {
            short8 af = *(const short8*)(wrow + kt*32);
            acc = __builtin_amdgcn_mfma_f32_16x16x32_bf16(af, xf[kt], acc, 0, 0, 0);
        }
        int which = jt >> 3;               // 0 q, 1 k, 2 v
        int h = jt & 7;
        float scale = (which == 0) ? 0.25f : 1.0f;
        f32x4 res;
        #pragma unroll
        for (int r = 0; r < 4; ++r) {
            int jg = which*128 + h*16 + quad*4 + r;
            res[r] = (acc[r] + bias[jg]) * scale;
        }
        long bh = b*H + h;
        if (which == 2) {
            // V transposed + interleaved: Vt[bh][dh][blk*32 + kk]
            short* vt = is_im ? Vtim : Vtre;
            int tloc = tb & 31, tblk = tb & ~31;
            int kk = (tloc < 16) ? (2*tloc) : (2*(tloc-16)+1);
            #pragma unroll
            for (int r = 0; r < 4; ++r)
                vt[(bh*DH + quad*4 + r)*T + tblk + kk] = bf16s(res[r]);
        } else {
            short* qk = (which == 0) ? Qpk : Kpk;
            short4s pk;
            #pragma unroll
            for (int r = 0; r < 4; ++r) pk[r] = bf16s(res[r]);
            *(short4s*)&qk[(bh*T + tb)*32 + is_im*16 + quad*4] = pk;
        }
    }
}

// ---------------------------------------------------------------------------
// Kernel 3: MFMA flash attention. KEY FIX vs r5: the ds_read of P(i-1)
// precedes the ds_writes of P(i) in PROGRAM ORDER (LDS completes in-order
// per wave -- r5's read-after-write order drained the whole exp chain every
// iteration). Loop body: [read P(i-1), PV(i-1)] -> [loads i+1] ->
// [scores(i), exp, write P(i)]. Loop-carried deps: accumulators only.
// ---------------------------------------------------------------------------
__global__ __launch_bounds__(256) void attn_mfma_kernel(
    const short* __restrict__ Qpk, const short* __restrict__ Kpk,
    const short* __restrict__ Vtre, const short* __restrict__ Vtim,
    short* __restrict__ Opk)
{
    // per-wave double-buffered P: 16 rows x 40 shorts (80B rows)
    __shared__ __align__(16) short Pb[4][2][16*40];

    int id   = blockIdx.x;
    int bh   = id & 63;
    int q0   = (id >> 6) * 64;
    int tid  = threadIdx.x;
    int wave = tid >> 6;
    int lane = tid & 63;
    int col  = lane & 15;
    int quad = lane >> 4;

    long kq_base = (long)bh * T * 32;
    long vt_base = (long)bh * DH * T + (long)col * T;

    short8 qfrag = *(const short8*)&Qpk[kq_base + (long)(q0 + wave*16 + col)*32 + quad*8];

    const short* Kb = &Kpk[kq_base];
    const short* Vr = &Vtre[vt_base];
    const short* Vi = &Vtim[vt_base];

    short8 ones;
    #pragma unroll
    for (int i = 0; i < 8; ++i) ones[i] = (short)0x3F80;   // bf16 1.0

    f32x4 oaccr = {0.f,0.f,0.f,0.f};
    f32x4 oacci = {0.f,0.f,0.f,0.f};
    f32x4 lacc  = {0.f,0.f,0.f,0.f};
    const f32x4 zero = {0.f,0.f,0.f,0.f};
    short* Pw0 = &Pb[wave][0][0];
    short* Pw1 = &Pb[wave][1][0];

    // ---- prologue: tile 0 scores, then prefetch tile 1 ----
    short8 kf0_cur = *(const short8*)&Kb[(long)(col)*32 + quad*8];
    short8 kf1_cur = *(const short8*)&Kb[(long)(16 + col)*32 + quad*8];
    short8 vr_prev = *(const short8*)&Vr[quad*8];           // V tile 0
    short8 vi_prev = *(const short8*)&Vi[quad*8];

    {
        f32x4 s0 = __builtin_amdgcn_mfma_f32_16x16x32_bf16(qfrag, kf0_cur, zero, 0, 0, 0);
        f32x4 s1 = __builtin_amdgcn_mfma_f32_16x16x32_bf16(qfrag, kf1_cur, zero, 0, 0, 0);
        #pragma unroll
        for (int r = 0; r < 4; ++r) {
            float2 p; p.x = __expf(s0[r]); p.y = __expf(s1[r]);
            *(__hip_bfloat162*)&Pw0[(quad*4 + r)*40 + col*2] = __float22bfloat162_rn(p);
        }
    }
    kf0_cur = *(const short8*)&Kb[(long)(32 + col)*32 + quad*8];      // K tile 1
    kf1_cur = *(const short8*)&Kb[(long)(32 + 16 + col)*32 + quad*8];
    short8 vr_cur = *(const short8*)&Vr[32 + quad*8];                 // V tile 1
    short8 vi_cur = *(const short8*)&Vi[32 + quad*8];

    #pragma unroll 2
    for (int i = 1; i < 32; ++i) {
        // stage 1: PV + rowsum for tile i-1 (ds_read FIRST -- only waits on
        // writes issued one full iteration ago)
        const short* Pr = ((i - 1) & 1) ? Pw1 : Pw0;
        short8 af = *(const short8*)&Pr[col*40 + quad*8];
        oaccr = __builtin_amdgcn_mfma_f32_16x16x32_bf16(af, vr_prev, oaccr, 0, 0, 0);
        oacci = __builtin_amdgcn_mfma_f32_16x16x32_bf16(af, vi_prev, oacci, 0, 0, 0);
        lacc  = __builtin_amdgcn_mfma_f32_16x16x32_bf16(af, ones, lacc, 0, 0, 0);

        // stage 2: prefetch tile i+1 (OOB at i=31 lands in adjacent ws arrays)
        int k1 = (i + 1) * 32;
        short8 kf0n = *(const short8*)&Kb[(long)(k1 + col)*32 + quad*8];
        short8 kf1n = *(const short8*)&Kb[(long)(k1 + 16 + col)*32 + quad*8];
        short8 vrn  = *(const short8*)&Vr[k1 + quad*8];
        short8 vin  = *(const short8*)&Vi[k1 + quad*8];

        // stage 3: scores + exp for tile i, packed-bf16 P into LDS
        f32x4 s0 = __builtin_amdgcn_mfma_f32_16x16x32_bf16(qfrag, kf0_cur, zero, 0, 0, 0);
        f32x4 s1 = __builtin_amdgcn_mfma_f32_16x16x32_bf16(qfrag, kf1_cur, zero, 0, 0, 0);
        short* Pw = (i & 1) ? Pw1 : Pw0;
        #pragma unroll
        for (int r = 0; r < 4; ++r) {
            float2 p; p.x = __expf(s0[r]); p.y = __expf(s1[r]);
            *(__hip_bfloat162*)&Pw[(quad*4 + r)*40 + col*2] = __float22bfloat162_rn(p);
        }

        // rotate
        vr_prev = vr_cur; vi_prev = vi_cur;
        vr_cur = vrn; vi_cur = vin;
        kf0_cur = kf0n; kf1_cur = kf1n;
    }
    // epilogue: PV for tile 31
    {
        const short* Pr = (31 & 1) ? Pw1 : Pw0;
        short8 af = *(const short8*)&Pr[col*40 + quad*8];
        oaccr = __builtin_amdgcn_mfma_f32_16x16x32_bf16(af, vr_prev, oaccr, 0, 0, 0);
        oacci = __builtin_amdgcn_mfma_f32_16x16x32_bf16(af, vi_prev, oacci, 0, 0, 0);
        lacc  = __builtin_amdgcn_mfma_f32_16x16x32_bf16(af, ones, lacc, 0, 0, 0);
    }

    int b = bh >> 3, h = bh & 7;
    #pragma unroll
    for (int r = 0; r < 4; ++r) {
        float inv = 1.0f / lacc[r];           // rowsum(q) replicated across cols
        int q = q0 + wave*16 + quad*4 + r;
        long orow = ((long)(b*T + q))*256 + h*16 + col;
        Opk[orow]       = bf16s(oaccr[r] * inv);
        Opk[orow + 128] = bf16s(oacci[r] * inv);
    }
}

// ---------------------------------------------------------------------------
// Kernel 4: MFMA output projection, conversion-free B-operand from Opk.
// D[j][t] = sum_k Wf[j][k]*O[t][k], K=256. Scatter-store to out [2,B,E,T].
// ---------------------------------------------------------------------------
__global__ __launch_bounds__(256) void outproj_mfma_kernel(
    const short* __restrict__ Opk,
    const short* __restrict__ Wfp_re, const short* __restrict__ Wfp_im,
    const float* __restrict__ bf_re, const float* __restrict__ bf_im,
    float* __restrict__ out)
{
    int tid  = threadIdx.x;
    int wave = tid >> 6, lane = tid & 63;
    int col  = lane & 15, quad = lane >> 4;
    int ttile = blockIdx.x;            // [0,512)
    int b  = ttile >> 6;
    int tb = (ttile & 63) * 16 + col;
    long trow = (long)b*T + tb;

    short8 xf[8];
    #pragma unroll
    for (int kt = 0; kt < 8; ++kt)
        xf[kt] = *(const short8*)&Opk[trow*256 + kt*32 + quad*8];

    const f32x4 zero = {0.f,0.f,0.f,0.f};
    #pragma unroll
    for (int ni = 0; ni < 4; ++ni) {
        int nt = wave * 4 + ni;            // [0,16)
        int is_im = nt >= 8;
        int jt = is_im ? nt - 8 : nt;      // [0,8)
        const short* Wsel = is_im ? Wfp_im : Wfp_re;
        const short* wrow = &Wsel[(jt*16 + col)*256 + quad*8];
        f32x4 acc = zero;
        #pragma unroll
        for (int kt = 0; kt < 8; ++kt) {
            short8 af = *(const short8*)(wrow + kt*32);
            acc = __builtin_amdgcn_mfma_f32_16x16x32_bf16(af, xf[kt], acc, 0, 0, 0);
        }
        const float* bias = is_im ? bf_im : bf_re;
        long part = is_im ? (long)B*E*T : 0;
        #pragma unroll
        for (int r = 0; r < 4; ++r) {
            int j = jt*16 + quad*4 + r;
            out[part + ((long)(b*E + j))*T + tb] = acc[r] + bias[j];
        }
    }
}

// ---------------------------------------------------------------------------
extern "C" void kernel_launch(void* const* d_in, const int* in_sizes, int n_in,
                              void* d_out, int out_size, void* d_ws, size_t ws_size,
                              hipStream_t stream)
{
    const float* x_re    = (const float*)d_in[0];
    const float* x_im    = (const float*)d_in[1];
    const float* win_re  = (const float*)d_in[2];
    const float* win_im  = (const float*)d_in[3];
    const float* bin_re  = (const float*)d_in[4];
    const float* bin_im  = (const float*)d_in[5];
    const float* wout_re = (const float*)d_in[6];
    const float* wout_im = (const float*)d_in[7];
    const float* bout_re = (const float*)d_in[8];
    const float* bout_im = (const float*)d_in[9];
    const float* wt_re   = (const float*)d_in[10];
    const float* wt_im   = (const float*)d_in[11];
    const float* bt_re   = (const float*)d_in[12];
    const float* bt_im   = (const float*)d_in[13];
    float* out = (float*)d_out;

    // workspace layout (shorts/floats)
    short* Qpk  = (short*)d_ws;                       // 64*1024*32 = 2M shorts
    short* Kpk  = Qpk + (long)B*H*T*32;
    short* Vtre = Kpk + (long)B*H*T*32;               // 64*16*1024 = 1M shorts
    short* Vtim = Vtre + (long)B*H*DH*T;
    short* Opk  = Vtim + (long)B*H*DH*T;              // 8*1024*256 = 2M shorts
    short* Wp_re  = Opk + (long)B*T*256;
    short* Wp_im  = Wp_re + E3*256;
    short* Wfp_re = Wp_im + E3*256;
    short* Wfp_im = Wfp_re + E*256;
    float* bf_re  = (float*)(Wfp_im + E*256);
    float* bf_im  = bf_re + E;

    pack_win_kernel<<<dim3(E3*E/256), dim3(256), 0, stream>>>(
        win_re, win_im, Wp_re, Wp_im);

    fuse_weights_kernel<<<dim3(E*E/256), dim3(256), 0, stream>>>(
        wout_re, wout_im, bout_re, bout_im, wt_re, wt_im, bt_re, bt_im,
        Wfp_re, Wfp_im, bf_re, bf_im);

    qkv_mfma_kernel<<<dim3(T*B/16*2), dim3(256), 0, stream>>>(
        x_re, x_im, Wp_re, Wp_im, bin_re, bin_im,
        Qpk, Kpk, Vtre, Vtim);

    attn_mfma_kernel<<<dim3((T/64) * B*H), dim3(256), 0, stream>>>(
        Qpk, Kpk, Vtre, Vtim, Opk);

    outproj_mfma_kernel<<<dim3(T*B/16), dim3(256), 0, stream>>>(
        Opk, Wfp_re, Wfp_im, bf_re, bf_im, out);
}